// Round 14
// baseline (123.838 us; speedup 1.0000x reference)
//
#include <hip/hip_runtime.h>
#include <cstdint>
#include <cstddef>

// out[64,197,768] = concat(cls, patchify(images[64,3,224,224]) @ W^T + b)
// v8 = v4's gemm EXACTLY (1-phase, 24KB LDS, 256thr/4x(32x64) waves, XCD-bijective
//      swizzle, nblk-inner) with A staged directly from fp32 images in-register
//      (float4 -> cvt -> ds_write_b64), deleting the 57.8MB imgb round-trip.
//      Prep shrinks to W-convert + cls only (336 blocks).
//      v5/v6/v7 all regressed: the 24-waves/CU TLP is what hides latency — don't trade it.
#define MTOT 12544   // 64*196 GEMM rows
#define KTOT 768
#define NTOT 768

typedef float  f32x4  __attribute__((ext_vector_type(4)));
typedef __bf16 bf16x4 __attribute__((ext_vector_type(4)));
typedef __bf16 bf16x8 __attribute__((ext_vector_type(8)));

// ---------------- Prep: W fp32->bf16 + cls rows (images no longer staged) ----------------
#define W_ELEMS   (768*768)            // 589,824
#define W_BLOCKS  (W_ELEMS/8/256)      // 288
#define CLS_BLOCKS 48                  // 64*768 floats / 4 / 256

__global__ __launch_bounds__(256) void prep_kernel(
    const float* __restrict__ Wm, const float* __restrict__ cls,
    float* __restrict__ out, __bf16* __restrict__ Wb) {
  const int bid = blockIdx.x, tid = threadIdx.x;
  if (bid < W_BLOCKS) {
    const size_t q = (size_t)bid * 256 + tid;
    const float4 v0 = *(const float4*)(Wm + q * 8);
    const float4 v1 = *(const float4*)(Wm + q * 8 + 4);
    bf16x8 o;
    o[0]=(__bf16)v0.x; o[1]=(__bf16)v0.y; o[2]=(__bf16)v0.z; o[3]=(__bf16)v0.w;
    o[4]=(__bf16)v1.x; o[5]=(__bf16)v1.y; o[6]=(__bf16)v1.z; o[7]=(__bf16)v1.w;
    *(bf16x8*)(Wb + q * 8) = o;
  } else {
    const int t  = (bid - W_BLOCKS) * 256 + tid;
    const int bb = t / 192;             // 192 float4 per row
    const int r  = t - bb * 192;
    *(float4*)(out + (size_t)bb * 197 * 768 + r * 4) = *(const float4*)(cls + r * 4);
  }
}

// ---------------- GEMM: fused patchify-gather(fp32->bf16) + MFMA ----------------
// BM=64, BN=128, BK=64 -> grid 1176 blocks (6/CU by LDS, 24 waves/CU).
#define BM 64
#define BN 128
#define BK 64
#define NBLK_N 6    // 768/128
#define NWG   1176  // (MTOT/BM)*NBLK_N = 8 * 147 exactly
#define WG_PER_XCD 147

__device__ __forceinline__ void gload_lds16(const void* g, void* l) {
  __builtin_amdgcn_global_load_lds((__attribute__((address_space(1))) void*)(g),
                                   (__attribute__((address_space(3))) void*)(l),
                                   16, 0, 0);
}

__global__ __launch_bounds__(256) void gemm_kernel(
    const float* __restrict__ images, const __bf16* __restrict__ Wb,
    const float* __restrict__ bias, float* __restrict__ out) {
  __shared__ __bf16 As[2 * 64 * 32];   // 8 KB: [kstep][row 0..63][k 0..31]
  __shared__ __bf16 Bs[2 * 128 * 32];  // 16 KB

  const int tid  = threadIdx.x;
  // XCD-bijective swizzle (1176 = 8*147): each XCD owns a contiguous logical range.
  const int bx   = blockIdx.x;
  const int wgid = (bx & 7) * WG_PER_XCD + (bx >> 3);
  // nblk-inner: 6 consecutive wgid (same XCD) share one A-tile; W (1.2 MB bf16) L2-resident.
  const int mblk = wgid / NBLK_N;
  const int nblk = wgid - mblk * NBLK_N;
  const int m0 = mblk * BM;
  const int n0 = nblk * BN;
  const int wave = tid >> 6, lane = tid & 63;
  const int wm = (wave & 1) * 32;   // wave sub-tile 32(M) x 64(N)
  const int wn = (wave >> 1) * 64;
  const int lrow = lane & 15, lq = lane >> 4;

  f32x4 acc[2][4] = {};

  // ---- A staging from fp32 images, reg-staged with convert.
  //   thread: r = tid>>2 (tile row), f = tid&3 (pw quarter). Instr s=0..3 -> ph_rel = s.
  //   k_local = s*16 + f*4 + e (same (ph,pw) k-convention as v4's imgb gather).
  //   Global: per-instr offset s*224 floats; per-kt advance 896 / 47488 elems (= v4).
  const int ar = tid >> 2, af4 = tid & 3;
  const float* pA;
  {
    const int m = m0 + ar;
    const int bb = m / 196, p = m - bb * 196;
    const int pi = p / 14, pj = p - pi * 14;
    pA = images + ((size_t)(bb * 3 * 224 + pi * 16)) * 224 + pj * 16 + af4 * 4;
  }
  // LDS dests (elems): ks = s>>1, klo = (s&1)*16 + f*4
  __bf16* dA[4];
#pragma unroll
  for (int s = 0; s < 4; ++s)
    dA[s] = As + (s >> 1) * 2048 + ar * 32 + (s & 1) * 16 + af4 * 4;

  // ---- B staging: 1024 chunks; c = wave*256 + s*64 + lane (identical to v4)
  const __bf16* pB[4];
#pragma unroll
  for (int s = 0; s < 4; ++s) {
    const int c = wave * 256 + s * 64 + lane;
    const int kstep = c >> 9, rem = c & 511;
    const int h = rem >> 2, jc = rem & 3;
    pB[s] = Wb + (size_t)(n0 + h) * 768 + kstep * 32 + jc * 8;
  }
  __bf16* lB[4];
#pragma unroll
  for (int s = 0; s < 4; ++s) lB[s] = Bs + (wave * 256 + s * 64) * 8;

  for (int kt = 0; kt < KTOT / BK; ++kt) {   // 12 iterations
    // A: 4x float4 (coalesced 64B/4-lane groups), B: async global->LDS
    float4 va[4];
#pragma unroll
    for (int s = 0; s < 4; ++s) va[s] = *(const float4*)(pA + s * 224);
#pragma unroll
    for (int s = 0; s < 4; ++s) gload_lds16(pB[s], lB[s]);
    // convert + LDS write (b64 per chunk)
#pragma unroll
    for (int s = 0; s < 4; ++s) {
      bf16x4 cv;
      cv[0]=(__bf16)va[s].x; cv[1]=(__bf16)va[s].y;
      cv[2]=(__bf16)va[s].z; cv[3]=(__bf16)va[s].w;
      *(bf16x4*)dA[s] = cv;
    }
    // advance: +4 image rows within channel; at channel crossing +50176-2688 elems
    const int dAe = ((kt & 3) == 3) ? 47488 : 896;
    pA += dAe;
    pB[0] += BK; pB[1] += BK; pB[2] += BK; pB[3] += BK;
    __syncthreads();   // drains vmcnt (B tiles) + lgkm (A writes)

#pragma unroll
    for (int ks = 0; ks < 2; ++ks) {
      bf16x8 afr[2], bfr[4];
#pragma unroll
      for (int i = 0; i < 2; ++i)
        afr[i] = *(const bf16x8*)&As[ks * 2048 + (wm + i * 16 + lrow) * 32 + lq * 8];
#pragma unroll
      for (int j = 0; j < 4; ++j)
        bfr[j] = *(const bf16x8*)&Bs[ks * 4096 + (wn + j * 16 + lrow) * 32 + lq * 8];
#pragma unroll
      for (int i = 0; i < 2; ++i)
#pragma unroll
        for (int j = 0; j < 4; ++j)
          acc[i][j] = __builtin_amdgcn_mfma_f32_16x16x32_bf16(afr[i], bfr[j], acc[i][j], 0, 0, 0);
    }
    __syncthreads();
  }

  // Epilogue: C/D layout col=lane&15, row=(lane>>4)*4+r (round-0-verified convention)
#pragma unroll
  for (int j = 0; j < 4; ++j) {
    const int h  = n0 + wn + j * 16 + lrow;
    const float bv = bias[h];
#pragma unroll
    for (int i = 0; i < 2; ++i) {
      const int mb = m0 + wm + i * 16 + lq * 4;
#pragma unroll
      for (int r = 0; r < 4; ++r) {
        const int m  = mb + r;
        const int bb = m / 196, p = m - bb * 196;
        out[(size_t)(bb * 197 + 1 + p) * 768 + h] = acc[i][j][r] + bv;
      }
    }
  }
}

extern "C" void kernel_launch(void* const* d_in, const int* in_sizes, int n_in,
                              void* d_out, int out_size, void* d_ws, size_t ws_size,
                              hipStream_t stream) {
  const float* images = (const float*)d_in[0];  // [64,3,224,224]
  const float* Wm     = (const float*)d_in[1];  // [768,768]
  const float* b      = (const float*)d_in[2];  // [768]
  const float* cls    = (const float*)d_in[3];  // [1,768]
  float* out = (float*)d_out;                   // [64,197,768]

  __bf16* Wb = (__bf16*)d_ws;                   // 1.18 MB only
  (void)in_sizes; (void)n_in; (void)out_size; (void)ws_size;

  prep_kernel<<<W_BLOCKS + CLS_BLOCKS, 256, 0, stream>>>(Wm, cls, out, Wb);
  gemm_kernel<<<NWG, 256, 0, stream>>>(images, Wb, b, out);
}

// Round 15
// 113.368 us; speedup vs baseline: 1.0924x; 1.0924x over previous
//
#include <hip/hip_runtime.h>
#include <cstdint>
#include <cstddef>

// out[64,197,768] = concat(cls, patchify(images[64,3,224,224]) @ W^T + b)
// FINAL = v4 (measured 112.3 us, round 5): two-kernel structure — prep fp32->bf16
// (images, W) + cls rows; gemm with global_load_lds staging, 1-phase, 24 KB LDS
// (6 blocks/CU, 24 waves/CU), XCD-bijective block swizzle (1176 = 8*147), nblk-inner.
// Falsified alternatives: v5 dbuf-48K (118.2), v6 dbuf-24K (117.4), v7 64x64-waves
// (119.6), v8 fused-A (123.8). v4's TLP + L2-resident gload_lds staging is the
// measured local optimum of this design space.
#define MTOT 12544   // 64*196 GEMM rows
#define KTOT 768
#define NTOT 768

typedef float  f32x4  __attribute__((ext_vector_type(4)));
typedef __bf16 bf16x8 __attribute__((ext_vector_type(8)));

// ---------------- Prep: coalesced fp32->bf16 convert (images, W) + cls rows ----------------
#define IMG_ELEMS (64*3*224*224)       // 9,633,792
#define W_ELEMS   (768*768)            // 589,824
#define A_BLOCKS  (IMG_ELEMS/8/256)    // 4704
#define W_BLOCKS  (W_ELEMS/8/256)      // 288
#define CLS_BLOCKS 48                  // 64*768 floats / 4 / 256

__global__ __launch_bounds__(256) void prep_kernel(
    const float* __restrict__ images, const float* __restrict__ Wm,
    const float* __restrict__ cls, float* __restrict__ out,
    __bf16* __restrict__ imgb, __bf16* __restrict__ Wb) {
  const int bid = blockIdx.x, tid = threadIdx.x;
  if (bid < A_BLOCKS) {
    const size_t q = (size_t)bid * 256 + tid;
    const float4 v0 = *(const float4*)(images + q * 8);
    const float4 v1 = *(const float4*)(images + q * 8 + 4);
    bf16x8 o;
    o[0]=(__bf16)v0.x; o[1]=(__bf16)v0.y; o[2]=(__bf16)v0.z; o[3]=(__bf16)v0.w;
    o[4]=(__bf16)v1.x; o[5]=(__bf16)v1.y; o[6]=(__bf16)v1.z; o[7]=(__bf16)v1.w;
    *(bf16x8*)(imgb + q * 8) = o;
  } else if (bid < A_BLOCKS + W_BLOCKS) {
    const size_t q = (size_t)(bid - A_BLOCKS) * 256 + tid;
    const float4 v0 = *(const float4*)(Wm + q * 8);
    const float4 v1 = *(const float4*)(Wm + q * 8 + 4);
    bf16x8 o;
    o[0]=(__bf16)v0.x; o[1]=(__bf16)v0.y; o[2]=(__bf16)v0.z; o[3]=(__bf16)v0.w;
    o[4]=(__bf16)v1.x; o[5]=(__bf16)v1.y; o[6]=(__bf16)v1.z; o[7]=(__bf16)v1.w;
    *(bf16x8*)(Wb + q * 8) = o;
  } else {
    const int t  = (bid - A_BLOCKS - W_BLOCKS) * 256 + tid;
    const int bb = t / 192;             // 192 float4 per row
    const int r  = t - bb * 192;
    *(float4*)(out + (size_t)bb * 197 * 768 + r * 4) = *(const float4*)(cls + r * 4);
  }
}

// ---------------- GEMM: fused patchify-gather + MFMA ----------------
// BM=64, BN=128, BK=64 -> grid 196*6 = 1176 blocks (4.6/CU, 92% balance).
// LDS layout [kstep][row][32] keeps 64B row stride (conflict-optimal b128 reads).
#define BM 64
#define BN 128
#define BK 64
#define NBLK_N 6    // 768/128
#define NWG   1176  // (MTOT/BM)*NBLK_N = 8 * 147 exactly
#define WG_PER_XCD 147

__device__ __forceinline__ void gload_lds16(const void* g, void* l) {
  __builtin_amdgcn_global_load_lds((__attribute__((address_space(1))) void*)(g),
                                   (__attribute__((address_space(3))) void*)(l),
                                   16, 0, 0);
}

__global__ __launch_bounds__(256) void gemm_kernel(
    const __bf16* __restrict__ imgb, const __bf16* __restrict__ Wb,
    const float* __restrict__ bias, float* __restrict__ out) {
  __shared__ __bf16 As[2 * 64 * 32];   // 8 KB: [kstep][row 0..63][k 0..31]
  __shared__ __bf16 Bs[2 * 128 * 32];  // 16 KB

  const int tid  = threadIdx.x;
  // XCD-bijective swizzle: dispatch round-robins blockIdx across 8 XCDs; remap so each
  // XCD owns a CONTIGUOUS range of logical tiles. 1176 = 8*147 -> exact.
  const int bx   = blockIdx.x;
  const int wgid = (bx & 7) * WG_PER_XCD + (bx >> 3);
  // nblk-inner: 6 consecutive wgid (same XCD) share one A-tile; W (2.36 MB) L2-resident.
  const int mblk = wgid / NBLK_N;
  const int nblk = wgid - mblk * NBLK_N;
  const int m0 = mblk * BM;
  const int n0 = nblk * BN;
  const int wave = tid >> 6, lane = tid & 63;
  const int wm = (wave & 1) * 32;   // wave sub-tile 32(M) x 64(N)
  const int wn = (wave >> 1) * 64;
  const int lrow = lane & 15, lq = lane >> 4;

  f32x4 acc[2][4] = {};

  // A staging: 512 16B chunks; chunk c = wave*128 + s*64 + lane
  //   kstep=c>>8, row=(c&255)>>2, jc=c&3 -> k_in_tile = kstep*32+jc*8
  //   global: patchify gather; per-kt advance is a wave-uniform elem delta.
  const __bf16* pA[2];
#pragma unroll
  for (int s = 0; s < 2; ++s) {
    const int c = wave * 128 + s * 64 + lane;
    const int kstep = c >> 8, rem = c & 255;
    const int row = rem >> 2, jc = rem & 3;
    const int m = m0 + row;
    const int bb = m / 196, p = m - bb * 196;
    const int pi = p / 14, pj = p - pi * 14;
    const int ph_off = kstep * 2 + (jc >> 1);
    const int pw_off = (jc & 1) * 8;
    const size_t e = ((size_t)(bb * 3 * 224 + pi * 16 + ph_off)) * 224 + pj * 16 + pw_off;
    pA[s] = imgb + e;
  }
  // B staging: 1024 chunks; c = wave*256 + s*64 + lane
  const __bf16* pB[4];
#pragma unroll
  for (int s = 0; s < 4; ++s) {
    const int c = wave * 256 + s * 64 + lane;
    const int kstep = c >> 9, rem = c & 511;
    const int h = rem >> 2, jc = rem & 3;
    pB[s] = Wb + (size_t)(n0 + h) * 768 + kstep * 32 + jc * 8;
  }
  __bf16* lA[2];
  __bf16* lB[4];
#pragma unroll
  for (int s = 0; s < 2; ++s) lA[s] = As + (wave * 128 + s * 64) * 8;  // chunk*8 elems
#pragma unroll
  for (int s = 0; s < 4; ++s) lB[s] = Bs + (wave * 256 + s * 64) * 8;

  for (int kt = 0; kt < KTOT / BK; ++kt) {   // 12 iterations
#pragma unroll
    for (int s = 0; s < 2; ++s) gload_lds16(pA[s], lA[s]);
#pragma unroll
    for (int s = 0; s < 4; ++s) gload_lds16(pB[s], lB[s]);
    // advance: +4 image rows within channel; at channel crossing +50176-2688 elems
    const int dA = ((kt & 3) == 3) ? 47488 : 896;
    pA[0] += dA; pA[1] += dA;
    pB[0] += BK; pB[1] += BK; pB[2] += BK; pB[3] += BK;
    __syncthreads();   // drain vmcnt -> tiles complete

#pragma unroll
    for (int ks = 0; ks < 2; ++ks) {
      bf16x8 af[2], bf[4];
#pragma unroll
      for (int i = 0; i < 2; ++i)
        af[i] = *(const bf16x8*)&As[ks * 2048 + (wm + i * 16 + lrow) * 32 + lq * 8];
#pragma unroll
      for (int j = 0; j < 4; ++j)
        bf[j] = *(const bf16x8*)&Bs[ks * 4096 + (wn + j * 16 + lrow) * 32 + lq * 8];
#pragma unroll
      for (int i = 0; i < 2; ++i)
#pragma unroll
        for (int j = 0; j < 4; ++j)
          acc[i][j] = __builtin_amdgcn_mfma_f32_16x16x32_bf16(af[i], bf[j], acc[i][j], 0, 0, 0);
    }
    __syncthreads();
  }

  // Epilogue: C/D layout col=lane&15, row=(lane>>4)*4+r (round-0-verified convention)
#pragma unroll
  for (int j = 0; j < 4; ++j) {
    const int h  = n0 + wn + j * 16 + lrow;
    const float bv = bias[h];
#pragma unroll
    for (int i = 0; i < 2; ++i) {
      const int mb = m0 + wm + i * 16 + lq * 4;
#pragma unroll
      for (int r = 0; r < 4; ++r) {
        const int m  = mb + r;
        const int bb = m / 196, p = m - bb * 196;
        out[(size_t)(bb * 197 + 1 + p) * 768 + h] = acc[i][j][r] + bv;
      }
    }
  }
}

extern "C" void kernel_launch(void* const* d_in, const int* in_sizes, int n_in,
                              void* d_out, int out_size, void* d_ws, size_t ws_size,
                              hipStream_t stream) {
  const float* images = (const float*)d_in[0];  // [64,3,224,224]
  const float* Wm     = (const float*)d_in[1];  // [768,768]
  const float* b      = (const float*)d_in[2];  // [768]
  const float* cls    = (const float*)d_in[3];  // [1,768]
  float* out = (float*)d_out;                   // [64,197,768]

  __bf16* imgb = (__bf16*)d_ws;                   // 19.27 MB
  __bf16* Wb   = imgb + (size_t)IMG_ELEMS;        // 1.18 MB
  (void)in_sizes; (void)n_in; (void)out_size; (void)ws_size;

  prep_kernel<<<A_BLOCKS + W_BLOCKS + CLS_BLOCKS, 256, 0, stream>>>(
      images, Wm, cls, out, imgb, Wb);
  gemm_kernel<<<NWG, 256, 0, stream>>>(imgb, Wb, b, out);
}